// Round 14
// baseline (3912.077 us; speedup 1.0000x reference)
//
#include <hip/hip_runtime.h>
#include <hip/hip_bf16.h>

#define T_SEQ 512

typedef __attribute__((ext_vector_type(8))) short frag_ab;
typedef __attribute__((ext_vector_type(4))) float frag_cd;

static __device__ __forceinline__ unsigned short f2bf_rnd(float f){
    union { float f; unsigned u; } v; v.f = f;
    unsigned r = v.u + 0x7fffu + ((v.u >> 16) & 1u);
    return (unsigned short)(r >> 16);
}
static __device__ __forceinline__ float bf2f(unsigned short h){
    union { unsigned u; float f; } v; v.u = ((unsigned)h) << 16;
    return v.f;
}
static __device__ __forceinline__ float sigf(float v){
    return __builtin_amdgcn_rcpf(1.0f + __builtin_amdgcn_exp2f(-1.4426950408889634f * v));
}
static __device__ __forceinline__ float tanhf2(float v){
    return 2.0f * __builtin_amdgcn_rcpf(1.0f + __builtin_amdgcn_exp2f(-2.8853900817779268f * v)) - 1.0f;
}
static __device__ __forceinline__ frag_ab loadBfrag(const float* __restrict__ W, int ldk, int jcol, int k0){
    const float* p = W + jcol * ldk + k0;
    frag_ab r;
    #pragma unroll
    for (int i = 0; i < 8; ++i) r[i] = (short)f2bf_rnd(p[i]);
    return r;
}
static __device__ __forceinline__ frag_cd splat4(float v){ return frag_cd{v,v,v,v}; }

#define MFMA(a,b,c) __builtin_amdgcn_mfma_f32_16x16x32_bf16((a),(b),(c),0,0,0)

// Counted barrier: drain LDS only; in-flight global x loads cross the barrier.
// (R13 lesson: LDS mailbox flag-sync is strictly worse -- spin polls burn
// issue slots and add ~120cy/hop LDS latency to the dep chain; s_barrier
// sleeps waves for free.)
#define BAR() asm volatile("s_waitcnt lgkmcnt(0)\ns_barrier" ::: "memory")

// R14 = R12 structure (8-wave blocks, barrier/step, lo-free bf16 state) at
// batch-2 per block x 1024 blocks -> 4 blocks/CU (launch_bounds(512,8),
// VGPR<=64; R12 measured 60). Chip MFMA doubles (pipe was ~15% busy) to buy
// 4 independent anti-phase barrier domains per CU -- fills the ~600cy/step
// of exposed dependency latency that 2 domains couldn't.
// Batch mapping: A-frag LDS row = (b4&1) (rows {0,1,0,1} = batches), gate
// extraction stays literal [0] (reg0 row=4*lq -> batch lq&1); unique LDS
// writers are lanes lq<2.
__global__ __launch_bounds__(512, 8)
void gru_fusedD(const float* __restrict__ x,
                const float* __restrict__ Wih1, const float* __restrict__ Whh1,
                const float* __restrict__ bih1, const float* __restrict__ bhh1,
                const float* __restrict__ Wih2, const float* __restrict__ Whh2,
                const float* __restrict__ bih2, const float* __restrict__ bhh2,
                const float* __restrict__ Wfc,  const float* __restrict__ bfc,
                const float* __restrict__ Wout, const float* __restrict__ bout,
                float* __restrict__ out)
{
    __shared__ __align__(16) unsigned short RGhi[2][144];   // h1 ring [slot][b*72+col]
    __shared__ __align__(16) unsigned short XHI[4][144];    // x ring depth 4
    __shared__ __align__(16) unsigned short H2HI[2][80];    // h2 ring [slot][b*40+j]
    __shared__ float HFIN[64];
    __shared__ float FCS[32];

    const int tid  = threadIdx.x;
    const int wv   = tid >> 6;
    const int lane = tid & 63;
    const int lrow = lane & 15;
    const int lq   = lane >> 4;
    const int b4   = lrow >> 2;
    const int bbase = blockIdx.x * 2;
    const int hv   = (int)(blockIdx.x & 1);
    const bool isL1 = (wv < 4);
    const bool isL2 = (!isL1) && (((wv >> 1) & 1) == hv);
    const int mi   = wv & 1;

    for (int i = tid; i < 144; i += 512){ RGhi[1][i] = 0; }
    for (int i = tid; i < 80;  i += 512){ H2HI[1][i] = 0; }

    // prologue x staging: x(0)->slot0, x(1)->slot1 (2 batches x 64)
    if (tid < 256){
        const int s = tid >> 7, idx = tid & 127;
        const int b = idx >> 6, k = idx & 63;
        XHI[s][b*72 + k] = f2bf_rnd(x[((size_t)(bbase + b) * T_SEQ + s) * 64 + k]);
    }

    // role-unioned persistent registers
    frag_ab WF[12];
    frag_cd BF[4];

    if (isL1){
        const int col1 = wv*16 + lrow;
        #pragma unroll
        for (int kf = 0; kf < 2; ++kf){
            const int k0 = kf*32 + 8*lq;
            WF[0+kf]  = loadBfrag(Wih1, 64, col1,       k0);
            WF[2+kf]  = loadBfrag(Wih1, 64, 64  + col1, k0);
            WF[4+kf]  = loadBfrag(Wih1, 64, 128 + col1, k0);
            WF[6+kf]  = loadBfrag(Whh1, 64, col1,       k0);
            WF[8+kf]  = loadBfrag(Whh1, 64, 64  + col1, k0);
            WF[10+kf] = loadBfrag(Whh1, 64, 128 + col1, k0);
        }
        BF[0] = splat4(bih1[col1] + bhh1[col1]);
        BF[1] = splat4(bih1[64 + col1] + bhh1[64 + col1]);
        BF[2] = splat4(bih1[128 + col1]);
        BF[3] = splat4(bhh1[128 + col1]);
    } else if (isL2){
        const int c2 = mi*16 + lrow;
        #pragma unroll
        for (int kf = 0; kf < 2; ++kf){
            const int k0 = kf*32 + 8*lq;
            WF[0+kf] = loadBfrag(Wih2, 64, c2,      k0);
            WF[2+kf] = loadBfrag(Wih2, 64, 32 + c2, k0);
            WF[4+kf] = loadBfrag(Wih2, 64, 64 + c2, k0);
        }
        WF[6] = loadBfrag(Whh2, 32, c2,      8*lq);
        WF[7] = loadBfrag(Whh2, 32, 32 + c2, 8*lq);
        WF[8] = loadBfrag(Whh2, 32, 64 + c2, 8*lq);
        BF[0] = splat4(bih2[c2] + bhh2[c2]);
        BF[1] = splat4(bih2[32 + c2] + bhh2[32 + c2]);
        BF[2] = splat4(bih2[64 + c2]);
        BF[3] = splat4(bhh2[64 + c2]);
    }

    // x staging (XW pair): 1 float/thread (2 batches x 64 cols = 128 lanes)
    const int u   = mi*64 + lane;
    const int xb2 = u >> 6, xk2 = u & 63;
    const int xo2 = xb2*72 + xk2;
    const float* xld = x + ((size_t)(bbase + xb2) * T_SEQ + 4)*64 + xk2;
    float xp0 = 0.f, xp1 = 0.f;
    if (!isL1 && !isL2){
        xp0 = x[((size_t)(bbase + xb2) * T_SEQ + 2)*64 + xk2];
        xp1 = x[((size_t)(bbase + xb2) * T_SEQ + 3)*64 + xk2];
    }

    const int fo0 = (b4 & 1)*72 + 8*lq;   // A-frag row -> batch (b4&1)
    const int go2 = (b4 & 1)*40 + 8*lq;
    const int rgo = lq*72 + (wv & 3)*16 + lrow;   // valid writer: lq<2
    const int h2o = lq*40 + mi*16 + lrow;         // valid writer: lq<2

    float hs = 0.f;   // L1: h1(batch lq&1, col) ; L2: h2(batch lq&1, col)

    __syncthreads();   // full drain once

// SX = t&3 (x read slot; write slot SX^2), SP = t&1 (RG write / H2 read slot)
#define GSTEP(SX, SP, DO_L1, DO_L2, DO_X, DO_XLD) do{                         \
    if ((DO_X) && !isL1 && !isL2){                                            \
        float xn2 = 0.f;                                                      \
        if (DO_XLD){ xn2 = *xld; xld += 64; }                                 \
        XHI[(SX)^2][xo2] = f2bf_rnd(xp0);                                     \
        xp0 = xp1;                                                            \
        if (DO_XLD) xp1 = xn2;                                                \
    }                                                                         \
    if ((DO_L1) && isL1){                                                     \
        frag_ab hhf0, hhf1, xhf0, xhf1;                                       \
        hhf0 = *(const frag_ab*)(&RGhi[(SP)^1][fo0]);                         \
        hhf1 = *(const frag_ab*)(&RGhi[(SP)^1][fo0 + 32]);                    \
        xhf0 = *(const frag_ab*)(&XHI[SX][fo0]);                              \
        xhf1 = *(const frag_ab*)(&XHI[SX][fo0 + 32]);                         \
        __builtin_amdgcn_s_setprio(1);                                        \
        frag_cd A0, A1, A2, A3;                                               \
        A0 = MFMA(xhf0, WF[0], BF[0]); A0 = MFMA(xhf1, WF[1], A0);            \
        A0 = MFMA(hhf0, WF[6], A0);    A0 = MFMA(hhf1, WF[7], A0);            \
        A1 = MFMA(xhf0, WF[2], BF[1]); A1 = MFMA(xhf1, WF[3], A1);            \
        A1 = MFMA(hhf0, WF[8], A1);    A1 = MFMA(hhf1, WF[9], A1);            \
        A2 = MFMA(xhf0, WF[4], BF[2]); A2 = MFMA(xhf1, WF[5], A2);            \
        A3 = MFMA(hhf0, WF[10], BF[3]); A3 = MFMA(hhf1, WF[11], A3);          \
        __builtin_amdgcn_s_setprio(0);                                        \
        const float rg = sigf(A0[0]), zg = sigf(A1[0]);                       \
        const float ng = tanhf2(A2[0] + rg*A3[0]);                            \
        hs = ng + zg*(hs - ng);                                               \
        if (lq < 2) RGhi[SP][rgo] = f2bf_rnd(hs);                             \
    }                                                                         \
    if ((DO_L2) && isL2){                                                     \
        frag_ab hhf0, hhf1, g2hf;                                             \
        hhf0 = *(const frag_ab*)(&RGhi[(SP)^1][fo0]);                         \
        hhf1 = *(const frag_ab*)(&RGhi[(SP)^1][fo0 + 32]);                    \
        g2hf = *(const frag_ab*)(&H2HI[SP][go2]);                             \
        __builtin_amdgcn_s_setprio(1);                                        \
        frag_cd B0, B1, B2, B3;                                               \
        B0 = MFMA(hhf0, WF[0], BF[0]); B0 = MFMA(hhf1, WF[1], B0);            \
        B0 = MFMA(g2hf, WF[6], B0);                                           \
        B1 = MFMA(hhf0, WF[2], BF[1]); B1 = MFMA(hhf1, WF[3], B1);            \
        B1 = MFMA(g2hf, WF[7], B1);                                           \
        B2 = MFMA(hhf0, WF[4], BF[2]); B2 = MFMA(hhf1, WF[5], B2);            \
        B3 = MFMA(g2hf, WF[8], BF[3]);                                        \
        __builtin_amdgcn_s_setprio(0);                                        \
        const float rv = sigf(B0[0]), zv = sigf(B1[0]);                       \
        const float nv = tanhf2(B2[0] + rv*B3[0]);                            \
        hs = nv + zv*(hs - nv);                                               \
        if (lq < 2) H2HI[(SP)^1][h2o] = f2bf_rnd(hs);                         \
    }                                                                         \
    BAR();                                                                    \
}while(0)

    // phase 0 (L1 + staging; no L2 yet)
    GSTEP(0, 0, true, false, true, true);

    // phases 1..504: 126 iterations x 4 (all ring slots literal)
    #pragma unroll 1
    for (int i = 0; i < 126; ++i){
        GSTEP(1, 1, true, true, true, true);
        GSTEP(2, 0, true, true, true, true);
        GSTEP(3, 1, true, true, true, true);
        GSTEP(0, 0, true, true, true, true);
    }

    // tail phases 505..512
    GSTEP(1, 1, true, true, true,  true);    // 505: loads row 509
    GSTEP(2, 0, true, true, true,  true);    // 506: loads row 510
    GSTEP(3, 1, true, true, true,  true);    // 507: loads row 511
    GSTEP(0, 0, true, true, true,  false);   // 508: write x(510)
    GSTEP(1, 1, true, true, true,  false);   // 509: write x(511)
    GSTEP(2, 0, true, true, false, false);   // 510
    GSTEP(3, 1, true, true, false, false);   // 511
    GSTEP(0, 0, false, true, false, false);  // 512: L2 final step
#undef GSTEP

    // head: h2(511) in H2 slot 1 (2 batches x 32 units)
    if (tid < 64){
        const int r = tid >> 5, c = tid & 31;
        HFIN[r*32 + c] = bf2f(H2HI[1][r*40 + c]);
    }
    __syncthreads();
    if (tid < 32){
        const int b = tid >> 4, f = tid & 15;
        float s = bfc[f];
        #pragma unroll
        for (int k = 0; k < 32; ++k) s += HFIN[b*32 + k] * Wfc[f*32 + k];
        FCS[b*16 + f] = fmaxf(s, 0.f);
    }
    __syncthreads();
    if (tid < 2){
        float o = bout[0];
        #pragma unroll
        for (int f = 0; f < 16; ++f) o += FCS[tid*16 + f] * Wout[f];
        out[bbase + tid] = o;
    }
}

extern "C" void kernel_launch(void* const* d_in, const int* in_sizes, int n_in,
                              void* d_out, int out_size, void* d_ws, size_t ws_size,
                              hipStream_t stream) {
    const float* x    = (const float*)d_in[0];
    const float* Wih1 = (const float*)d_in[1];
    const float* Whh1 = (const float*)d_in[2];
    const float* bih1 = (const float*)d_in[3];
    const float* bhh1 = (const float*)d_in[4];
    const float* Wih2 = (const float*)d_in[5];
    const float* Whh2 = (const float*)d_in[6];
    const float* bih2 = (const float*)d_in[7];
    const float* bhh2 = (const float*)d_in[8];
    const float* Wfc  = (const float*)d_in[9];
    const float* bfc  = (const float*)d_in[10];
    const float* Wout = (const float*)d_in[11];
    const float* bout = (const float*)d_in[12];

    gru_fusedD<<<1024, 512, 0, stream>>>(x, Wih1, Whh1, bih1, bhh1,
                                         Wih2, Whh2, bih2, bhh2,
                                         Wfc, bfc, Wout, bout, (float*)d_out);
}

// Round 15
// 255.932 us; speedup vs baseline: 15.2856x; 15.2856x over previous
//
#include <hip/hip_runtime.h>
#include <hip/hip_bf16.h>

#define T_SEQ 512

typedef __attribute__((ext_vector_type(8))) short frag_ab;
typedef __attribute__((ext_vector_type(4))) float frag_cd;

static __device__ __forceinline__ unsigned short f2bf_rnd(float f){
    union { float f; unsigned u; } v; v.f = f;
    unsigned r = v.u + 0x7fffu + ((v.u >> 16) & 1u);
    return (unsigned short)(r >> 16);
}
static __device__ __forceinline__ float bf2f(unsigned short h){
    union { unsigned u; float f; } v; v.u = ((unsigned)h) << 16;
    return v.f;
}
static __device__ __forceinline__ float sigf(float v){
    return __builtin_amdgcn_rcpf(1.0f + __builtin_amdgcn_exp2f(-1.4426950408889634f * v));
}
static __device__ __forceinline__ float tanhf2(float v){
    return 2.0f * __builtin_amdgcn_rcpf(1.0f + __builtin_amdgcn_exp2f(-2.8853900817779268f * v)) - 1.0f;
}
static __device__ __forceinline__ frag_ab loadBfrag(const float* __restrict__ W, int ldk, int jcol, int k0){
    const float* p = W + jcol * ldk + k0;
    frag_ab r;
    #pragma unroll
    for (int i = 0; i < 8; ++i) r[i] = (short)f2bf_rnd(p[i]);
    return r;
}
static __device__ __forceinline__ frag_cd splat4(float v){ return frag_cd{v,v,v,v}; }

#define MFMA(a,b,c) __builtin_amdgcn_mfma_f32_16x16x32_bf16((a),(b),(c),0,0,0)

// Counted barrier: drain LDS only; in-flight global x loads cross the barrier.
#define BAR() asm volatile("s_waitcnt lgkmcnt(0)\ns_barrier" ::: "memory")

// R15 = R12 (224us base: 8-wave blocks, batch-4, 512 blocks, 2 blocks/CU,
// counted barrier, lo-free bf16 state, literal ring slots) + L1 x-part
// software pipelining: step t's x-MFMAs (independent of h1(t-1)) run in
// phase t-1 into persistent accs PX0..2 that cross the barrier in registers.
// Phase t's post-barrier critical chain shrinks: ds_read 4->2 frags, MFMA
// chain 4->2 deep. Accumulation order per acc unchanged -> bit-identical.
// (R14 lesson: register footprint caps this design at 2 blocks/CU; 4-domain
// co-residency spills catastrophically. Do not raise launch_bounds min-waves.)
__global__ __launch_bounds__(512, 2)
void gru_fusedE(const float* __restrict__ x,
                const float* __restrict__ Wih1, const float* __restrict__ Whh1,
                const float* __restrict__ bih1, const float* __restrict__ bhh1,
                const float* __restrict__ Wih2, const float* __restrict__ Whh2,
                const float* __restrict__ bih2, const float* __restrict__ bhh2,
                const float* __restrict__ Wfc,  const float* __restrict__ bfc,
                const float* __restrict__ Wout, const float* __restrict__ bout,
                float* __restrict__ out)
{
    __shared__ __align__(16) unsigned short RGhi[2][288];
    __shared__ __align__(16) unsigned short XHI[4][288];
    __shared__ __align__(16) unsigned short H2HI[2][160];
    __shared__ float HFIN[128];
    __shared__ float FCS[64];

    const int tid  = threadIdx.x;
    const int wv   = tid >> 6;
    const int lane = tid & 63;
    const int lrow = lane & 15;
    const int lq   = lane >> 4;
    const int b4   = lrow >> 2;
    const int bbase = blockIdx.x * 4;
    const int hv   = (int)(blockIdx.x & 1);
    const bool isL1 = (wv < 4);
    const bool isL2 = (!isL1) && (((wv >> 1) & 1) == hv);
    const int mi   = wv & 1;

    for (int i = tid; i < 288; i += 512){ RGhi[1][i] = 0; }
    for (int i = tid; i < 160; i += 512){ H2HI[1][i] = 0; }

    // prologue x staging: x(0)->slot0, x(1)->slot1 (512 thr x 1 elem)
    {
        const int s = tid >> 8, idx = tid & 255;
        const int b = idx >> 6, k = idx & 63;
        XHI[s][b*72 + k] = f2bf_rnd(x[((size_t)(bbase + b) * T_SEQ + s) * 64 + k]);
    }

    // role-unioned persistent registers
    frag_ab WF[12];
    frag_cd BF[4];
    frag_cd PX0, PX1, PX2;   // L1: x-part accs for the NEXT step (cross-barrier)

    if (isL1){
        const int col1 = wv*16 + lrow;
        #pragma unroll
        for (int kf = 0; kf < 2; ++kf){
            const int k0 = kf*32 + 8*lq;
            WF[0+kf]  = loadBfrag(Wih1, 64, col1,       k0);
            WF[2+kf]  = loadBfrag(Wih1, 64, 64  + col1, k0);
            WF[4+kf]  = loadBfrag(Wih1, 64, 128 + col1, k0);
            WF[6+kf]  = loadBfrag(Whh1, 64, col1,       k0);
            WF[8+kf]  = loadBfrag(Whh1, 64, 64  + col1, k0);
            WF[10+kf] = loadBfrag(Whh1, 64, 128 + col1, k0);
        }
        BF[0] = splat4(bih1[col1] + bhh1[col1]);
        BF[1] = splat4(bih1[64 + col1] + bhh1[64 + col1]);
        BF[2] = splat4(bih1[128 + col1]);
        BF[3] = splat4(bhh1[128 + col1]);
    } else if (isL2){
        const int c2 = mi*16 + lrow;
        #pragma unroll
        for (int kf = 0; kf < 2; ++kf){
            const int k0 = kf*32 + 8*lq;
            WF[0+kf] = loadBfrag(Wih2, 64, c2,      k0);
            WF[2+kf] = loadBfrag(Wih2, 64, 32 + c2, k0);
            WF[4+kf] = loadBfrag(Wih2, 64, 64 + c2, k0);
        }
        WF[6] = loadBfrag(Whh2, 32, c2,      8*lq);
        WF[7] = loadBfrag(Whh2, 32, 32 + c2, 8*lq);
        WF[8] = loadBfrag(Whh2, 32, 64 + c2, 8*lq);
        BF[0] = splat4(bih2[c2] + bhh2[c2]);
        BF[1] = splat4(bih2[32 + c2] + bhh2[32 + c2]);
        BF[2] = splat4(bih2[64 + c2]);
        BF[3] = splat4(bhh2[64 + c2]);
    }

    // x staging (XW pair): 2 floats/thread, 2-phase register hold
    const int u   = mi*64 + lane;
    const int xb2 = u >> 5, xk2 = (u & 31)*2;
    const int xo2 = xb2*72 + xk2;
    const float* xld = x + ((size_t)(bbase + xb2) * T_SEQ + 4)*64 + xk2;
    float2 xp0 = {0.f,0.f}, xp1 = {0.f,0.f};
    if (!isL1 && !isL2){
        xp0 = *(const float2*)(x + ((size_t)(bbase + xb2) * T_SEQ + 2)*64 + xk2);
        xp1 = *(const float2*)(x + ((size_t)(bbase + xb2) * T_SEQ + 3)*64 + xk2);
    }

    const int fo0 = b4*72 + 8*lq;
    const int go2 = b4*40 + 8*lq;
    const int rgo = lq*72 + (wv & 3)*16 + lrow;
    const int h2o = lq*40 + mi*16 + lrow;

    float hs = 0.f;

    __syncthreads();   // full drain once

    // L1 pipelining prologue: x-part for step 0 (XHI slot 0)
    if (isL1){
        const frag_ab xhf0 = *(const frag_ab*)(&XHI[0][fo0]);
        const frag_ab xhf1 = *(const frag_ab*)(&XHI[0][fo0 + 32]);
        PX0 = MFMA(xhf0, WF[0], BF[0]); PX0 = MFMA(xhf1, WF[1], PX0);
        PX1 = MFMA(xhf0, WF[2], BF[1]); PX1 = MFMA(xhf1, WF[3], PX1);
        PX2 = MFMA(xhf0, WF[4], BF[2]); PX2 = MFMA(xhf1, WF[5], PX2);
    }

// SX = t&3 (x read slot for NEXT-step prefetch uses ((SX)+1)&3; XW write slot
// SX^2), SP = t&1 (RG write / H2 read slot). DO_XP: prefetch x-part for t+1.
#define GSTEP(SX, SP, DO_L1, DO_L2, DO_X, DO_XLD, DO_XP) do{                  \
    if ((DO_X) && !isL1 && !isL2){                                            \
        float2 xn2;                                                           \
        if (DO_XLD){ xn2 = *(const float2*)xld; xld += 64; }                  \
        const unsigned short a0 = f2bf_rnd(xp0.x), a1 = f2bf_rnd(xp0.y);      \
        *(unsigned*)(&XHI[(SX)^2][xo2]) = (unsigned)a0 | ((unsigned)a1 << 16);\
        xp0 = xp1;                                                            \
        if (DO_XLD) xp1 = xn2;                                                \
    }                                                                         \
    if ((DO_L1) && isL1){                                                     \
        frag_ab hhf0, hhf1;                                                   \
        hhf0 = *(const frag_ab*)(&RGhi[(SP)^1][fo0]);                         \
        hhf1 = *(const frag_ab*)(&RGhi[(SP)^1][fo0 + 32]);                    \
        __builtin_amdgcn_s_setprio(1);                                        \
        frag_cd A0, A1, A3;                                                   \
        A0 = MFMA(hhf0, WF[6], PX0);    A0 = MFMA(hhf1, WF[7], A0);           \
        A1 = MFMA(hhf0, WF[8], PX1);    A1 = MFMA(hhf1, WF[9], A1);           \
        A3 = MFMA(hhf0, WF[10], BF[3]); A3 = MFMA(hhf1, WF[11], A3);          \
        __builtin_amdgcn_s_setprio(0);                                        \
        const float rg = sigf(A0[0]), zg = sigf(A1[0]);                       \
        const float ng = tanhf2(PX2[0] + rg*A3[0]);                           \
        hs = ng + zg*(hs - ng);                                               \
        RGhi[SP][rgo] = f2bf_rnd(hs);                                         \
        if (DO_XP){   /* x-part for step t+1 into PX (fills phase tail) */    \
            const frag_ab xhf0 = *(const frag_ab*)(&XHI[((SX)+1)&3][fo0]);    \
            const frag_ab xhf1 = *(const frag_ab*)(&XHI[((SX)+1)&3][fo0+32]); \
            __builtin_amdgcn_s_setprio(1);                                    \
            PX0 = MFMA(xhf0, WF[0], BF[0]); PX0 = MFMA(xhf1, WF[1], PX0);     \
            PX1 = MFMA(xhf0, WF[2], BF[1]); PX1 = MFMA(xhf1, WF[3], PX1);     \
            PX2 = MFMA(xhf0, WF[4], BF[2]); PX2 = MFMA(xhf1, WF[5], PX2);     \
            __builtin_amdgcn_s_setprio(0);                                    \
        }                                                                     \
    }                                                                         \
    if ((DO_L2) && isL2){                                                     \
        frag_ab hhf0, hhf1, g2hf;                                             \
        hhf0 = *(const frag_ab*)(&RGhi[(SP)^1][fo0]);                         \
        hhf1 = *(const frag_ab*)(&RGhi[(SP)^1][fo0 + 32]);                    \
        g2hf = *(const frag_ab*)(&H2HI[SP][go2]);                             \
        __builtin_amdgcn_s_setprio(1);                                        \
        frag_cd B0, B1, B2, B3;                                               \
        B0 = MFMA(hhf0, WF[0], BF[0]); B0 = MFMA(hhf1, WF[1], B0);            \
        B0 = MFMA(g2hf, WF[6], B0);                                           \
        B1 = MFMA(hhf0, WF[2], BF[1]); B1 = MFMA(hhf1, WF[3], B1);            \
        B1 = MFMA(g2hf, WF[7], B1);                                           \
        B2 = MFMA(hhf0, WF[4], BF[2]); B2 = MFMA(hhf1, WF[5], B2);            \
        B3 = MFMA(g2hf, WF[8], BF[3]);                                        \
        __builtin_amdgcn_s_setprio(0);                                        \
        const float rv = sigf(B0[0]), zv = sigf(B1[0]);                       \
        const float nv = tanhf2(B2[0] + rv*B3[0]);                            \
        hs = nv + zv*(hs - nv);                                               \
        H2HI[(SP)^1][h2o] = f2bf_rnd(hs);                                     \
    }                                                                         \
    BAR();                                                                    \
}while(0)

    // phase 0 (L1 + staging; no L2 yet)
    GSTEP(0, 0, true, false, true, true, true);

    // phases 1..504: 126 iterations x 4 (all ring slots literal)
    #pragma unroll 1
    for (int i = 0; i < 126; ++i){
        GSTEP(1, 1, true, true, true, true, true);
        GSTEP(2, 0, true, true, true, true, true);
        GSTEP(3, 1, true, true, true, true, true);
        GSTEP(0, 0, true, true, true, true, true);
    }

    // tail phases 505..512
    GSTEP(1, 1, true, true, true,  true,  true);    // 505: loads row 509
    GSTEP(2, 0, true, true, true,  true,  true);    // 506: loads row 510
    GSTEP(3, 1, true, true, true,  true,  true);    // 507: loads row 511
    GSTEP(0, 0, true, true, true,  false, true);    // 508: write x(510)
    GSTEP(1, 1, true, true, true,  false, true);    // 509: write x(511)
    GSTEP(2, 0, true, true, false, false, true);    // 510
    GSTEP(3, 1, true, true, false, false, false);   // 511: last L1 step
    GSTEP(0, 0, false, true, false, false, false);  // 512: L2 final step
#undef GSTEP

    // head: h2(511) in H2 slot 1
    if (tid < 128){
        const int r = tid >> 5, c = tid & 31;
        HFIN[r*32 + c] = bf2f(H2HI[1][r*40 + c]);
    }
    __syncthreads();
    if (tid < 64){
        const int b = tid >> 4, f = tid & 15;
        float s = bfc[f];
        #pragma unroll
        for (int k = 0; k < 32; ++k) s += HFIN[b*32 + k] * Wfc[f*32 + k];
        FCS[b*16 + f] = fmaxf(s, 0.f);
    }
    __syncthreads();
    if (tid < 4){
        float o = bout[0];
        #pragma unroll
        for (int f = 0; f < 16; ++f) o += FCS[tid*16 + f] * Wout[f];
        out[bbase + tid] = o;
    }
}

extern "C" void kernel_launch(void* const* d_in, const int* in_sizes, int n_in,
                              void* d_out, int out_size, void* d_ws, size_t ws_size,
                              hipStream_t stream) {
    const float* x    = (const float*)d_in[0];
    const float* Wih1 = (const float*)d_in[1];
    const float* Whh1 = (const float*)d_in[2];
    const float* bih1 = (const float*)d_in[3];
    const float* bhh1 = (const float*)d_in[4];
    const float* Wih2 = (const float*)d_in[5];
    const float* Whh2 = (const float*)d_in[6];
    const float* bih2 = (const float*)d_in[7];
    const float* bhh2 = (const float*)d_in[8];
    const float* Wfc  = (const float*)d_in[9];
    const float* bfc  = (const float*)d_in[10];
    const float* Wout = (const float*)d_in[11];
    const float* bout = (const float*)d_in[12];

    gru_fusedE<<<512, 512, 0, stream>>>(x, Wih1, Whh1, bih1, bhh1,
                                        Wih2, Whh2, bih2, bhh2,
                                        Wfc, bfc, Wout, bout, (float*)d_out);
}

// Round 16
// 225.930 us; speedup vs baseline: 17.3155x; 1.1328x over previous
//
#include <hip/hip_runtime.h>
#include <hip/hip_bf16.h>

#define T_SEQ 512

typedef __attribute__((ext_vector_type(8))) short frag_ab;
typedef __attribute__((ext_vector_type(4))) float frag_cd;

static __device__ __forceinline__ unsigned short f2bf_rnd(float f){
    union { float f; unsigned u; } v; v.f = f;
    unsigned r = v.u + 0x7fffu + ((v.u >> 16) & 1u);
    return (unsigned short)(r >> 16);
}
static __device__ __forceinline__ float bf2f(unsigned short h){
    union { unsigned u; float f; } v; v.u = ((unsigned)h) << 16;
    return v.f;
}
static __device__ __forceinline__ float sigf(float v){
    return __builtin_amdgcn_rcpf(1.0f + __builtin_amdgcn_exp2f(-1.4426950408889634f * v));
}
static __device__ __forceinline__ float tanhf2(float v){
    return 2.0f * __builtin_amdgcn_rcpf(1.0f + __builtin_amdgcn_exp2f(-2.8853900817779268f * v)) - 1.0f;
}
static __device__ __forceinline__ frag_ab loadBfrag(const float* __restrict__ W, int ldk, int jcol, int k0){
    const float* p = W + jcol * ldk + k0;
    frag_ab r;
    #pragma unroll
    for (int i = 0; i < 8; ++i) r[i] = (short)f2bf_rnd(p[i]);
    return r;
}
static __device__ __forceinline__ frag_cd splat4(float v){ return frag_cd{v,v,v,v}; }

#define MFMA(a,b,c) __builtin_amdgcn_mfma_f32_16x16x32_bf16((a),(b),(c),0,0,0)

// Counted barrier: drain LDS only; in-flight global x loads cross the barrier.
#define BAR() asm volatile("s_waitcnt lgkmcnt(0)\ns_barrier" ::: "memory")

// R16 = exact revert to R12 (best measured: 224us). Session evidence says this
// structure's local optimum:
//  - R13 flag-sync (LDS mailboxes): 369us — spin-polls burn issue slots, +120cy
//    LDS hop on dep chain. s_barrier sleeps waves for free.
//  - R14 4 domains/CU via launch_bounds(512,8): 3912us — register capacity
//    caps this design at 2 blocks/CU; forcing more spills to scratch.
//  - R15 x-part software pipelining: 256us — under a barrier convoy the step
//    period is each wave's TOTAL phase work; moving MFMAs head->tail removes
//    nothing and adds cross-barrier register deps.
// Remaining gap (step ~1050cy vs ~450cy issue) = barrier-convoy latency floor
// of a 512-step dependent recurrence at 2 domains/CU, <=128 regs/wave.
__global__ __launch_bounds__(512, 2)
void gru_fusedB(const float* __restrict__ x,
                const float* __restrict__ Wih1, const float* __restrict__ Whh1,
                const float* __restrict__ bih1, const float* __restrict__ bhh1,
                const float* __restrict__ Wih2, const float* __restrict__ Whh2,
                const float* __restrict__ bih2, const float* __restrict__ bhh2,
                const float* __restrict__ Wfc,  const float* __restrict__ bfc,
                const float* __restrict__ Wout, const float* __restrict__ bout,
                float* __restrict__ out)
{
    __shared__ __align__(16) unsigned short RGhi[2][288];
    __shared__ __align__(16) unsigned short XHI[4][288];
    __shared__ __align__(16) unsigned short H2HI[2][160];
    __shared__ float HFIN[128];
    __shared__ float FCS[64];

    const int tid  = threadIdx.x;
    const int wv   = tid >> 6;
    const int lane = tid & 63;
    const int lrow = lane & 15;
    const int lq   = lane >> 4;
    const int b4   = lrow >> 2;          // A-frag row -> batch (remap)
    const int bbase = blockIdx.x * 4;
    const int hv   = (int)(blockIdx.x & 1);
    const bool isL1 = (wv < 4);
    const bool isL2 = (!isL1) && (((wv >> 1) & 1) == hv);
    const bool isXW = (!isL1) && !isL2;

    for (int i = tid; i < 288; i += 512){ RGhi[1][i] = 0; }
    for (int i = tid; i < 160; i += 512){ H2HI[1][i] = 0; }

    // prologue x staging: x(0)->slot0, x(1)->slot1 (512 thr x 1 elem)
    {
        const int s = tid >> 8, idx = tid & 255;
        const int b = idx >> 6, k = idx & 63;
        XHI[s][b*72 + k] = f2bf_rnd(x[((size_t)(bbase + b) * T_SEQ + s) * 64 + k]);
    }

    // role-unioned persistent registers
    frag_ab WF[12];
    frag_cd BF[4];

    if (isL1){
        const int col1 = wv*16 + lrow;
        #pragma unroll
        for (int kf = 0; kf < 2; ++kf){
            const int k0 = kf*32 + 8*lq;
            WF[0+kf]  = loadBfrag(Wih1, 64, col1,       k0);
            WF[2+kf]  = loadBfrag(Wih1, 64, 64  + col1, k0);
            WF[4+kf]  = loadBfrag(Wih1, 64, 128 + col1, k0);
            WF[6+kf]  = loadBfrag(Whh1, 64, col1,       k0);
            WF[8+kf]  = loadBfrag(Whh1, 64, 64  + col1, k0);
            WF[10+kf] = loadBfrag(Whh1, 64, 128 + col1, k0);
        }
        BF[0] = splat4(bih1[col1] + bhh1[col1]);
        BF[1] = splat4(bih1[64 + col1] + bhh1[64 + col1]);
        BF[2] = splat4(bih1[128 + col1]);
        BF[3] = splat4(bhh1[128 + col1]);
    } else if (isL2){
        const int c2 = (wv & 1)*16 + lrow;
        #pragma unroll
        for (int kf = 0; kf < 2; ++kf){
            const int k0 = kf*32 + 8*lq;
            WF[0+kf] = loadBfrag(Wih2, 64, c2,      k0);
            WF[2+kf] = loadBfrag(Wih2, 64, 32 + c2, k0);
            WF[4+kf] = loadBfrag(Wih2, 64, 64 + c2, k0);
        }
        WF[6] = loadBfrag(Whh2, 32, c2,      8*lq);
        WF[7] = loadBfrag(Whh2, 32, 32 + c2, 8*lq);
        WF[8] = loadBfrag(Whh2, 32, 64 + c2, 8*lq);
        BF[0] = splat4(bih2[c2] + bhh2[c2]);
        BF[1] = splat4(bih2[32 + c2] + bhh2[32 + c2]);
        BF[2] = splat4(bih2[64 + c2]);
        BF[3] = splat4(bhh2[64 + c2]);
    }

    // x staging (staging pair): 2 floats/thread, 2-phase register hold
    const int u   = (wv & 1)*64 + lane;
    const int xb2 = u >> 5, xk2 = (u & 31)*2;
    const int xo2 = xb2*72 + xk2;
    const float* xld = x + ((size_t)(bbase + xb2) * T_SEQ + 4)*64 + xk2;
    float2 xp0 = {0.f,0.f}, xp1 = {0.f,0.f};
    if (isXW){
        xp0 = *(const float2*)(x + ((size_t)(bbase + xb2) * T_SEQ + 2)*64 + xk2);
        xp1 = *(const float2*)(x + ((size_t)(bbase + xb2) * T_SEQ + 3)*64 + xk2);
    }

    const int fo0 = b4*72 + 8*lq;        // A-frag read: batch = row>>2
    const int go2 = b4*40 + 8*lq;
    const int rgo = lq*72 + (wv & 3)*16 + lrow;   // writes unchanged (batch lq)
    const int h2o = lq*40 + (wv & 1)*16 + lrow;

    float hs = 0.f;

    __syncthreads();   // full drain once

// SX = t&3 (x read slot; write slot SX^2), SP = t&1 (RG write / H2 read slot)
#define GSTEP(SX, SP, DO_L1, DO_L2, DO_X, DO_XLD) do{                         \
    if ((DO_X) && isXW){                                                      \
        float2 xn2;                                                           \
        if (DO_XLD){ xn2 = *(const float2*)xld; xld += 64; }                  \
        const unsigned short a0 = f2bf_rnd(xp0.x), a1 = f2bf_rnd(xp0.y);      \
        *(unsigned*)(&XHI[(SX)^2][xo2]) = (unsigned)a0 | ((unsigned)a1 << 16);\
        xp0 = xp1;                                                            \
        if (DO_XLD) xp1 = xn2;                                                \
    }                                                                         \
    if ((DO_L1) && isL1){                                                     \
        frag_ab hhf0, hhf1, xhf0, xhf1;                                       \
        hhf0 = *(const frag_ab*)(&RGhi[(SP)^1][fo0]);                         \
        hhf1 = *(const frag_ab*)(&RGhi[(SP)^1][fo0 + 32]);                    \
        xhf0 = *(const frag_ab*)(&XHI[SX][fo0]);                              \
        xhf1 = *(const frag_ab*)(&XHI[SX][fo0 + 32]);                         \
        __builtin_amdgcn_s_setprio(1);                                        \
        frag_cd A0, A1, A2, A3;                                               \
        A0 = MFMA(xhf0, WF[0], BF[0]); A0 = MFMA(xhf1, WF[1], A0);            \
        A0 = MFMA(hhf0, WF[6], A0);    A0 = MFMA(hhf1, WF[7], A0);            \
        A1 = MFMA(xhf0, WF[2], BF[1]); A1 = MFMA(xhf1, WF[3], A1);            \
        A1 = MFMA(hhf0, WF[8], A1);    A1 = MFMA(hhf1, WF[9], A1);            \
        A2 = MFMA(xhf0, WF[4], BF[2]); A2 = MFMA(xhf1, WF[5], A2);            \
        A3 = MFMA(hhf0, WF[10], BF[3]); A3 = MFMA(hhf1, WF[11], A3);          \
        __builtin_amdgcn_s_setprio(0);                                        \
        const float rg = sigf(A0[0]), zg = sigf(A1[0]);                       \
        const float ng = tanhf2(A2[0] + rg*A3[0]);                            \
        hs = ng + zg*(hs - ng);                                               \
        RGhi[SP][rgo] = f2bf_rnd(hs);                                         \
    }                                                                         \
    if ((DO_L2) && isL2){                                                     \
        frag_ab hhf0, hhf1, g2hf;                                             \
        hhf0 = *(const frag_ab*)(&RGhi[(SP)^1][fo0]);                         \
        hhf1 = *(const frag_ab*)(&RGhi[(SP)^1][fo0 + 32]);                    \
        g2hf = *(const frag_ab*)(&H2HI[SP][go2]);                             \
        __builtin_amdgcn_s_setprio(1);                                        \
        frag_cd B0, B1, B2, B3;                                               \
        B0 = MFMA(hhf0, WF[0], BF[0]); B0 = MFMA(hhf1, WF[1], B0);            \
        B0 = MFMA(g2hf, WF[6], B0);                                           \
        B1 = MFMA(hhf0, WF[2], BF[1]); B1 = MFMA(hhf1, WF[3], B1);            \
        B1 = MFMA(g2hf, WF[7], B1);                                           \
        B2 = MFMA(hhf0, WF[4], BF[2]); B2 = MFMA(hhf1, WF[5], B2);            \
        B3 = MFMA(g2hf, WF[8], BF[3]);                                        \
        __builtin_amdgcn_s_setprio(0);                                        \
        const float rv = sigf(B0[0]), zv = sigf(B1[0]);                       \
        const float nv = tanhf2(B2[0] + rv*B3[0]);                            \
        hs = nv + zv*(hs - nv);                                               \
        H2HI[(SP)^1][h2o] = f2bf_rnd(hs);                                     \
    }                                                                         \
    BAR();                                                                    \
}while(0)

    // phase 0 (L1 + staging; no L2 yet)
    GSTEP(0, 0, true, false, true, true);

    // phases 1..504: 126 iterations x 4 (all ring slots literal)
    #pragma unroll 1
    for (int i = 0; i < 126; ++i){
        GSTEP(1, 1, true, true, true, true);
        GSTEP(2, 0, true, true, true, true);
        GSTEP(3, 1, true, true, true, true);
        GSTEP(0, 0, true, true, true, true);
    }

    // tail phases 505..512
    GSTEP(1, 1, true, true, true,  true);    // 505: loads row 509
    GSTEP(2, 0, true, true, true,  true);    // 506: loads row 510
    GSTEP(3, 1, true, true, true,  true);    // 507: loads row 511
    GSTEP(0, 0, true, true, true,  false);   // 508: write x(510)
    GSTEP(1, 1, true, true, true,  false);   // 509: write x(511)
    GSTEP(2, 0, true, true, false, false);   // 510
    GSTEP(3, 1, true, true, false, false);   // 511
    GSTEP(0, 0, false, true, false, false);  // 512: L2 final step
#undef GSTEP

    // head: h2(511) in H2 slot 1
    if (tid < 128){
        const int r = tid >> 5, c = tid & 31;
        HFIN[r*32 + c] = bf2f(H2HI[1][r*40 + c]);
    }
    __syncthreads();
    if (tid < 64){
        const int b = tid >> 4, f = tid & 15;
        float s = bfc[f];
        #pragma unroll
        for (int k = 0; k < 32; ++k) s += HFIN[b*32 + k] * Wfc[f*32 + k];
        FCS[b*16 + f] = fmaxf(s, 0.f);
    }
    __syncthreads();
    if (tid < 4){
        float o = bout[0];
        #pragma unroll
        for (int f = 0; f < 16; ++f) o += FCS[tid*16 + f] * Wout[f];
        out[bbase + tid] = o;
    }
}

extern "C" void kernel_launch(void* const* d_in, const int* in_sizes, int n_in,
                              void* d_out, int out_size, void* d_ws, size_t ws_size,
                              hipStream_t stream) {
    const float* x    = (const float*)d_in[0];
    const float* Wih1 = (const float*)d_in[1];
    const float* Whh1 = (const float*)d_in[2];
    const float* bih1 = (const float*)d_in[3];
    const float* bhh1 = (const float*)d_in[4];
    const float* Wih2 = (const float*)d_in[5];
    const float* Whh2 = (const float*)d_in[6];
    const float* bih2 = (const float*)d_in[7];
    const float* bhh2 = (const float*)d_in[8];
    const float* Wfc  = (const float*)d_in[9];
    const float* bfc  = (const float*)d_in[10];
    const float* Wout = (const float*)d_in[11];
    const float* bout = (const float*)d_in[12];

    gru_fusedB<<<512, 512, 0, stream>>>(x, Wih1, Whh1, bih1, bhh1,
                                        Wih2, Whh2, bih2, bhh2,
                                        Wfc, bfc, Wout, bout, (float*)d_out);
}